// Round 6
// baseline (168.549 us; speedup 1.0000x reference)
//
#include <hip/hip_runtime.h>
#include <hip/hip_bf16.h>

// CorrelationNetwork — single fused kernel for MI355X (gfx950), round 10.
// R9 post-mortem: fusing worked (invariant 73->59us) but the kernel grew
// 29->46.7us: grid=256 -> 1 block/CU -> 2 waves/SIMD, Occupancy 18%, the
// serial prepass (scalar W1 loads + broadcast LDS reads + fmaf chains) is
// latency-bound with no TLP (VALUBusy 44%, ~25% issue efficiency).
// VGPR_Count=128 with no spill => 2 blocks/CU is feasible.
// R10: grid = 512 blocks (b, i-quarter; 8 tiles each), AiF shrunk to 16
// rows -> LDS 63.3KB/block (126.6/CU), __launch_bounds__(512,4) pins the
// 128-reg tier R9 already hit. Two blocks/CU interleave: one block's
// prepass stalls hide under the other's MFMA/VALU. Arithmetic verbatim R9.

typedef __bf16 bf16x8 __attribute__((ext_vector_type(8)));
typedef float f32x4 __attribute__((ext_vector_type(4)));

__global__ __launch_bounds__(512, 4) void fused_kernel(
    const float* __restrict__ af, const float* __restrict__ W1,
    const float* __restrict__ b1, const float* __restrict__ W2,
    const float* __restrict__ b2, const float* __restrict__ w3,
    const float* __restrict__ b3, const float* __restrict__ mw,
    float* __restrict__ out)
{
  __shared__ __align__(16) float fl[64 * 64];      // af[b][n][0..63], 16 KB
  __shared__ __align__(16) float AjF[64 * 132];    // 33.8 KB, pad-132
  __shared__ __align__(16) float AiF[16 * 132];    // 8.45 KB
  __shared__ float b2s[128], w3s[128];
  __shared__ float part[2][2][128];                // [tile&1][wm][row]

  const int tid  = threadIdx.x;
  const int lane = tid & 63;
  const int wave = tid >> 6;            // 0..7
  const int c = lane & 15, g = lane >> 4;
  const int wm = wave & 1;              // w2col half (64 cols)
  const int wn = wave >> 1;             // row quarter (32 rows)

  const int blk = blockIdx.x;
  const int b   = blk >> 2;             // 0..127
  const int iq  = blk & 3;              // i-quarter (8 i-pairs)
  const int ip0 = iq << 3;

  // ---- softmax of mixing weights (block 0, wave 0 only)
  if (blk == 0 && tid < 64) {
    float v = mw[tid];
    float m = v;
    for (int off = 32; off > 0; off >>= 1) m = fmaxf(m, __shfl_xor(m, off));
    float e = expf(v - m);
    float s = e;
    for (int off = 32; off > 0; off >>= 1) s += __shfl_xor(s, off);
    out[128 * 64 * 64 + tid] = e / s;
  }

  // ---- stage fl = af[b][0..63][0..63] (16 KB) + b2s/w3s, coalesced
  {
    const float4* srcQ = (const float4*)(af + (b << 13));
#pragma unroll
    for (int p = 0; p < 2; ++p) {
      const int idx = (p << 9) + tid;            // 0..1023 float4s
      const int n = idx >> 4, e = idx & 15;
      *(float4*)&fl[(n << 6) + (e << 2)] = srcQ[(n << 5) + e];
    }
    if (tid < 128) b2s[tid] = b2[tid];
    else if (tid < 256) w3s[tid - 128] = w3[tid - 128];
  }

  // ---- W2 fragments straight from global f32 (L2-resident), manual RNE ->
  // bf16 (bit-identical to old W2T path). Lane (c,g) frag element e:
  // m = wm*64+mt*16+c, k = kt*32+g*8+e, value = W2[k][m].
  bf16x8 w2r[4][4];
  {
    union U { unsigned short s; __bf16 h; };
#pragma unroll
    for (int mt = 0; mt < 4; ++mt)
#pragma unroll
      for (int kt = 0; kt < 4; ++kt) {
        const float* wp = W2 + (((kt << 5) + (g << 3)) << 7) +
                          (wm << 6) + (mt << 4) + c;
#pragma unroll
        for (int e = 0; e < 8; ++e) {
          unsigned u = __float_as_uint(wp[e << 7]);
          u += 0x7fffu + ((u >> 16) & 1u);
          U cv; cv.s = (unsigned short)(u >> 16);
          w2r[mt][kt][e] = cv.h;
        }
      }
  }

  const int h = tid & 127;
  const int q = tid >> 7;                        // 0..3
  const float b1h = b1[h];
  const float bias3 = b3[0];

  __syncthreads();                               // fl/b2s/w3s ready

  // ---- prepass (setup's exact fmaf chains, W1 register-cached).
  // Thread (h,q): Aj rows q*16..q*16+15 (W1[64:]), Ai rows q*4..q*4+3 (W1[:64]).
  {
    float w1c[64];
    // Aj half: W1 rows 64..127, column h
#pragma unroll
    for (int f = 0; f < 64; ++f) w1c[f] = W1[((64 + f) << 7) + h];
#pragma unroll
    for (int qd = 0; qd < 4; ++qd) {
      const int r0 = (q << 4) + (qd << 2);
      float a0 = 0.f, a1 = 0.f, a2 = 0.f, a3 = 0.f;
#pragma unroll
      for (int fq = 0; fq < 16; ++fq) {
        const float w0  = w1c[fq * 4 + 0];
        const float w1v = w1c[fq * 4 + 1];
        const float w2v = w1c[fq * 4 + 2];
        const float w3v = w1c[fq * 4 + 3];
        const float4 f0 = *(const float4*)&fl[((r0 + 0) << 6) + (fq << 2)];
        const float4 f1 = *(const float4*)&fl[((r0 + 1) << 6) + (fq << 2)];
        const float4 f2 = *(const float4*)&fl[((r0 + 2) << 6) + (fq << 2)];
        const float4 f3 = *(const float4*)&fl[((r0 + 3) << 6) + (fq << 2)];
        a0 = fmaf(f0.x, w0, fmaf(f0.y, w1v, fmaf(f0.z, w2v, fmaf(f0.w, w3v, a0))));
        a1 = fmaf(f1.x, w0, fmaf(f1.y, w1v, fmaf(f1.z, w2v, fmaf(f1.w, w3v, a1))));
        a2 = fmaf(f2.x, w0, fmaf(f2.y, w1v, fmaf(f2.z, w2v, fmaf(f2.w, w3v, a2))));
        a3 = fmaf(f3.x, w0, fmaf(f3.y, w1v, fmaf(f3.z, w2v, fmaf(f3.w, w3v, a3))));
      }
      AjF[(r0 + 0) * 132 + h] = a0;
      AjF[(r0 + 1) * 132 + h] = a1;
      AjF[(r0 + 2) * 132 + h] = a2;
      AjF[(r0 + 3) * 132 + h] = a3;
    }
    // Ai half: W1 rows 0..63, +b1; fl row = iq*16 + local row
#pragma unroll
    for (int f = 0; f < 64; ++f) w1c[f] = W1[(f << 7) + h];
    {
      const int r0 = q << 2;                     // rows q*4..q*4+3
      const int fr = (iq << 4) + r0;
      float a0 = 0.f, a1 = 0.f, a2 = 0.f, a3 = 0.f;
#pragma unroll
      for (int fq = 0; fq < 16; ++fq) {
        const float w0  = w1c[fq * 4 + 0];
        const float w1v = w1c[fq * 4 + 1];
        const float w2v = w1c[fq * 4 + 2];
        const float w3v = w1c[fq * 4 + 3];
        const float4 f0 = *(const float4*)&fl[((fr + 0) << 6) + (fq << 2)];
        const float4 f1 = *(const float4*)&fl[((fr + 1) << 6) + (fq << 2)];
        const float4 f2 = *(const float4*)&fl[((fr + 2) << 6) + (fq << 2)];
        const float4 f3 = *(const float4*)&fl[((fr + 3) << 6) + (fq << 2)];
        a0 = fmaf(f0.x, w0, fmaf(f0.y, w1v, fmaf(f0.z, w2v, fmaf(f0.w, w3v, a0))));
        a1 = fmaf(f1.x, w0, fmaf(f1.y, w1v, fmaf(f1.z, w2v, fmaf(f1.w, w3v, a1))));
        a2 = fmaf(f2.x, w0, fmaf(f2.y, w1v, fmaf(f2.z, w2v, fmaf(f2.w, w3v, a2))));
        a3 = fmaf(f3.x, w0, fmaf(f3.y, w1v, fmaf(f3.z, w2v, fmaf(f3.w, w3v, a3))));
      }
      AiF[(r0 + 0) * 132 + h] = a0 + b1h;
      AiF[(r0 + 1) * 132 + h] = a1 + b1h;
      AiF[(r0 + 2) * 132 + h] = a2 + b1h;
      AiF[(r0 + 3) * 132 + h] = a3 + b1h;
    }
  }

  __syncthreads();                               // AjF/AiF ready

  // ---- tile-invariant Aj fragments -> registers (verbatim R7)
  f32x4 ajr[4][2][2];
#pragma unroll
  for (int kt = 0; kt < 4; ++kt)
#pragma unroll
    for (int tn = 0; tn < 2; ++tn) {
      const int j = ((wn << 5) + (tn << 4) + c) & 63;
      const float* ajb = &AjF[j * 132 + (g << 3) + (kt << 5)];
      ajr[kt][tn][0] = *(const f32x4*)(ajb);
      ajr[kt][tn][1] = *(const f32x4*)(ajb + 4);
    }

  const int i_sel = wn >> 1;                     // row>=64 -> second i of pair

  for (int t = 0; t < 8; ++t) {
    const float* aib = &AiF[((t << 1) + i_sel) * 132 + (g << 3)];

    f32x4 acc[4][2];
#pragma unroll
    for (int mt = 0; mt < 4; ++mt) {
      const f32x4 bv = *(const f32x4*)&b2s[(wm << 6) + (mt << 4) + (g << 2)];
      acc[mt][0] = bv;
      acc[mt][1] = bv;
    }

#pragma unroll
    for (int kt = 0; kt < 4; ++kt) {
      const f32x4 a0 = *(const f32x4*)(aib + (kt << 5));
      const f32x4 a1 = *(const f32x4*)(aib + (kt << 5) + 4);
      bf16x8 hv[2];
#pragma unroll
      for (int tn = 0; tn < 2; ++tn) {
        const f32x4 h0  = a0 + ajr[kt][tn][0];
        const f32x4 h1v = a1 + ajr[kt][tn][1];
#pragma unroll
        for (int e = 0; e < 4; ++e) {
          hv[tn][e]     = (__bf16)fmaxf(h0[e], 0.f);
          hv[tn][e + 4] = (__bf16)fmaxf(h1v[e], 0.f);
        }
      }
#pragma unroll
      for (int mt = 0; mt < 4; ++mt)
#pragma unroll
        for (int tn = 0; tn < 2; ++tn)
          acc[mt][tn] = __builtin_amdgcn_mfma_f32_16x16x32_bf16(
              w2r[mt][kt], hv[tn], acc[mt][tn], 0, 0, 0);
    }

    float s0 = 0.f, s1 = 0.f;
#pragma unroll
    for (int mt = 0; mt < 4; ++mt) {
      const f32x4 wv3 = *(const f32x4*)&w3s[(wm << 6) + (mt << 4) + (g << 2)];
#pragma unroll
      for (int p = 0; p < 4; ++p) {
        s0 = fmaf(fmaxf(acc[mt][0][p], 0.f), wv3[p], s0);
        s1 = fmaf(fmaxf(acc[mt][1][p], 0.f), wv3[p], s1);
      }
    }
    s0 += __shfl_xor(s0, 16);
    s0 += __shfl_xor(s0, 32);
    s1 += __shfl_xor(s1, 16);
    s1 += __shfl_xor(s1, 32);

    const int pb = t & 1;
    if (g == 0) {                                // 16 lanes, conflict-free
      part[pb][wm][(wn << 5) + c]      = s0;
      part[pb][wm][(wn << 5) + 16 + c] = s1;
    }

    __syncthreads();                             // one barrier per tile

    if (tid < 128) {
      const float v = part[pb][0][tid] + part[pb][1][tid] + bias3;
      out[(b << 12) + ((ip0 + t) << 7) + tid] = 1.f / (1.f + __expf(-v));
    }
  }
}

extern "C" void kernel_launch(void* const* d_in, const int* in_sizes, int n_in,
                              void* d_out, int out_size, void* d_ws,
                              size_t ws_size, hipStream_t stream)
{
  const float* af = (const float*)d_in[0];   // (128,64,128)
  const float* W1 = (const float*)d_in[1];   // (128,128)
  const float* b1 = (const float*)d_in[2];   // (128,)
  const float* W2 = (const float*)d_in[3];   // (128,128)
  const float* b2 = (const float*)d_in[4];   // (128,)
  const float* w3 = (const float*)d_in[5];   // (128,)
  const float* b3 = (const float*)d_in[6];   // (1,)
  const float* mw = (const float*)d_in[7];   // (64,)
  float* out = (float*)d_out;                // 524288 corr + 64 weights

  (void)d_ws; (void)ws_size;
  // one kernel: 512 blocks (2/CU), block = (b, i-quarter), 8 tiles each
  fused_kernel<<<512, 512, 0, stream>>>(af, W1, b1, W2, b2, w3, b3, mw, out);
}

// Round 7
// 103.897 us; speedup vs baseline: 1.6223x; 1.6223x over previous
//
#include <hip/hip_runtime.h>
#include <hip/hip_bf16.h>

// CorrelationNetwork — single fused kernel for MI355X (gfx950), round 11.
// R10 post-mortem: (512,4) = 128-reg cap; the w2r(64)+ajr(32)+acc(32) body
// needs ~190 -> spilled (VGPR=64, FETCH 280MB, WRITE 71MB) exactly like R5.
// Law: register-cached W2 requires the (512,2) tier. To get 2 blocks/CU
// (R9 showed prepass is latency-bound at 18% occupancy, ~25% issue eff),
// shrink the live set instead: W2 -> LDS (R4/R6's swizzled W2s, proven
// under a 128 cap), keep ajr+acc in regs (~100 peak). LDS fits 2/CU by
// OVERLAYING W2s on fl (fl dead after prepass; W2 gathered f32->RNE bf16
// -> swizzled LDS after the prepass barrier): 32+33+8.25+1+4 = 78.3 KB.
// Arithmetic verbatim R9/R10 -> absmax must stay 0.00390625.

typedef __bf16 bf16x8 __attribute__((ext_vector_type(8)));
typedef float f32x4 __attribute__((ext_vector_type(4)));

__global__ __launch_bounds__(512, 4) void fused_kernel(
    const float* __restrict__ af, const float* __restrict__ W1,
    const float* __restrict__ b1, const float* __restrict__ W2,
    const float* __restrict__ b2, const float* __restrict__ w3,
    const float* __restrict__ b3, const float* __restrict__ mw,
    float* __restrict__ out)
{
  // W2s (32 KB, tile phase) overlays fl (16 KB, prepass staging)
  __shared__ __align__(16) unsigned short W2s[128 * 128];  // 32 KB
  float* const fl = (float*)W2s;                           // alias, 16 KB used
  __shared__ __align__(16) float AjF[64 * 132];            // 33 KB, pad-132
  __shared__ __align__(16) float AiF[16 * 132];            // 8.25 KB
  __shared__ float b2s[128], w3s[128];
  __shared__ float part[2][2][128];                        // [tile&1][wm][row]

  const int tid  = threadIdx.x;
  const int lane = tid & 63;
  const int wave = tid >> 6;            // 0..7
  const int c = lane & 15, g = lane >> 4;
  const int wm = wave & 1;              // w2col half (64 cols)
  const int wn = wave >> 1;             // row quarter (32 rows)

  const int blk = blockIdx.x;
  const int b   = blk >> 2;             // 0..127
  const int iq  = blk & 3;              // i-quarter (8 i-pairs)
  const int ip0 = iq << 3;

  // ---- softmax of mixing weights (block 0, wave 0 only)
  if (blk == 0 && tid < 64) {
    float v = mw[tid];
    float m = v;
    for (int off = 32; off > 0; off >>= 1) m = fmaxf(m, __shfl_xor(m, off));
    float e = expf(v - m);
    float s = e;
    for (int off = 32; off > 0; off >>= 1) s += __shfl_xor(s, off);
    out[128 * 64 * 64 + tid] = e / s;
  }

  // ---- stage fl = af[b][0..63][0..63] (16 KB) + b2s/w3s, coalesced
  {
    const float4* srcQ = (const float4*)(af + (b << 13));
#pragma unroll
    for (int p = 0; p < 2; ++p) {
      const int idx = (p << 9) + tid;            // 0..1023 float4s
      const int n = idx >> 4, e = idx & 15;
      *(float4*)&fl[(n << 6) + (e << 2)] = srcQ[(n << 5) + e];
    }
    if (tid < 128) b2s[tid] = b2[tid];
    else if (tid < 256) w3s[tid - 128] = w3[tid - 128];
  }

  const int h = tid & 127;
  const int q = tid >> 7;                        // 0..3
  const float b1h = b1[h];
  const float bias3 = b3[0];

  __syncthreads();                               // fl/b2s/w3s ready

  // ---- prepass (setup's exact fmaf chains, W1 register-cached).
  // Thread (h,q): Aj rows q*16..q*16+15 (W1[64:]), Ai rows q*4..q*4+3 (W1[:64]).
  {
    float w1c[64];
    // Aj half: W1 rows 64..127, column h
#pragma unroll
    for (int f = 0; f < 64; ++f) w1c[f] = W1[((64 + f) << 7) + h];
#pragma unroll
    for (int qd = 0; qd < 4; ++qd) {
      const int r0 = (q << 4) + (qd << 2);
      float a0 = 0.f, a1 = 0.f, a2 = 0.f, a3 = 0.f;
#pragma unroll
      for (int fq = 0; fq < 16; ++fq) {
        const float w0  = w1c[fq * 4 + 0];
        const float w1v = w1c[fq * 4 + 1];
        const float w2v = w1c[fq * 4 + 2];
        const float w3v = w1c[fq * 4 + 3];
        const float4 f0 = *(const float4*)&fl[((r0 + 0) << 6) + (fq << 2)];
        const float4 f1 = *(const float4*)&fl[((r0 + 1) << 6) + (fq << 2)];
        const float4 f2 = *(const float4*)&fl[((r0 + 2) << 6) + (fq << 2)];
        const float4 f3 = *(const float4*)&fl[((r0 + 3) << 6) + (fq << 2)];
        a0 = fmaf(f0.x, w0, fmaf(f0.y, w1v, fmaf(f0.z, w2v, fmaf(f0.w, w3v, a0))));
        a1 = fmaf(f1.x, w0, fmaf(f1.y, w1v, fmaf(f1.z, w2v, fmaf(f1.w, w3v, a1))));
        a2 = fmaf(f2.x, w0, fmaf(f2.y, w1v, fmaf(f2.z, w2v, fmaf(f2.w, w3v, a2))));
        a3 = fmaf(f3.x, w0, fmaf(f3.y, w1v, fmaf(f3.z, w2v, fmaf(f3.w, w3v, a3))));
      }
      AjF[(r0 + 0) * 132 + h] = a0;
      AjF[(r0 + 1) * 132 + h] = a1;
      AjF[(r0 + 2) * 132 + h] = a2;
      AjF[(r0 + 3) * 132 + h] = a3;
    }
    // Ai half: W1 rows 0..63, +b1; fl row = iq*16 + local row
#pragma unroll
    for (int f = 0; f < 64; ++f) w1c[f] = W1[(f << 7) + h];
    {
      const int r0 = q << 2;                     // rows q*4..q*4+3
      const int fr = (iq << 4) + r0;
      float a0 = 0.f, a1 = 0.f, a2 = 0.f, a3 = 0.f;
#pragma unroll
      for (int fq = 0; fq < 16; ++fq) {
        const float w0  = w1c[fq * 4 + 0];
        const float w1v = w1c[fq * 4 + 1];
        const float w2v = w1c[fq * 4 + 2];
        const float w3v = w1c[fq * 4 + 3];
        const float4 f0 = *(const float4*)&fl[((fr + 0) << 6) + (fq << 2)];
        const float4 f1 = *(const float4*)&fl[((fr + 1) << 6) + (fq << 2)];
        const float4 f2 = *(const float4*)&fl[((fr + 2) << 6) + (fq << 2)];
        const float4 f3 = *(const float4*)&fl[((fr + 3) << 6) + (fq << 2)];
        a0 = fmaf(f0.x, w0, fmaf(f0.y, w1v, fmaf(f0.z, w2v, fmaf(f0.w, w3v, a0))));
        a1 = fmaf(f1.x, w0, fmaf(f1.y, w1v, fmaf(f1.z, w2v, fmaf(f1.w, w3v, a1))));
        a2 = fmaf(f2.x, w0, fmaf(f2.y, w1v, fmaf(f2.z, w2v, fmaf(f2.w, w3v, a2))));
        a3 = fmaf(f3.x, w0, fmaf(f3.y, w1v, fmaf(f3.z, w2v, fmaf(f3.w, w3v, a3))));
      }
      AiF[(r0 + 0) * 132 + h] = a0 + b1h;
      AiF[(r0 + 1) * 132 + h] = a1 + b1h;
      AiF[(r0 + 2) * 132 + h] = a2 + b1h;
      AiF[(r0 + 3) * 132 + h] = a3 + b1h;
    }
  }

  __syncthreads();                    // AjF/AiF ready; fl reads done (fl dead)

  // ---- W2 gather: f32 global -> RNE bf16 -> swizzled W2s (overlays fl).
  // Wave (wm, kt=wn); lane (c,g) handles mt=0..3, elems e=0..7:
  // m = wm*64+mt*16+c, k = kt*32+g*8+e, chunk' = (kt*4+g)^c (= R6's es).
  {
    union U { unsigned short s; __bf16 h; };
    const int ktw = wn;
#pragma unroll
    for (int mt = 0; mt < 4; ++mt) {
      const int m = (wm << 6) + (mt << 4) + c;
      const float* wp = W2 + (((ktw << 5) + (g << 3)) << 7) + m;
      bf16x8 v;
#pragma unroll
      for (int e = 0; e < 8; ++e) {
        unsigned u = __float_as_uint(wp[e << 7]);
        u += 0x7fffu + ((u >> 16) & 1u);
        U cv; cv.s = (unsigned short)(u >> 16);
        v[e] = cv.h;
      }
      *(bf16x8*)&W2s[(m << 7) + ((((ktw << 2) + g) ^ c) << 3)] = v;
    }
  }

  // ---- tile-invariant Aj fragments -> registers (reads AjF, overlaps gather)
  f32x4 ajr[4][2][2];
#pragma unroll
  for (int kt = 0; kt < 4; ++kt)
#pragma unroll
    for (int tn = 0; tn < 2; ++tn) {
      const int j = ((wn << 5) + (tn << 4) + c) & 63;
      const float* ajb = &AjF[j * 132 + (g << 3) + (kt << 5)];
      ajr[kt][tn][0] = *(const f32x4*)(ajb);
      ajr[kt][tn][1] = *(const f32x4*)(ajb + 4);
    }

  __syncthreads();                               // W2s ready

  const int i_sel = wn >> 1;                     // row>=64 -> second i of pair

  for (int t = 0; t < 8; ++t) {
    const float* aib = &AiF[((t << 1) + i_sel) * 132 + (g << 3)];

    f32x4 acc[4][2];
#pragma unroll
    for (int mt = 0; mt < 4; ++mt) {
      const f32x4 bv = *(const f32x4*)&b2s[(wm << 6) + (mt << 4) + (g << 2)];
      acc[mt][0] = bv;
      acc[mt][1] = bv;
    }

#pragma unroll
    for (int kt = 0; kt < 4; ++kt) {
      // W2 frags from swizzled LDS (R6-proven access pattern)
      const int es = ((kt << 2) + g) ^ c;
      bf16x8 wv[4];
#pragma unroll
      for (int mt = 0; mt < 4; ++mt)
        wv[mt] = *(const bf16x8*)&W2s[(((wm << 6) + (mt << 4) + c) << 7) + (es << 3)];

      const f32x4 a0 = *(const f32x4*)(aib + (kt << 5));
      const f32x4 a1 = *(const f32x4*)(aib + (kt << 5) + 4);
      bf16x8 hv[2];
#pragma unroll
      for (int tn = 0; tn < 2; ++tn) {
        const f32x4 h0  = a0 + ajr[kt][tn][0];
        const f32x4 h1v = a1 + ajr[kt][tn][1];
#pragma unroll
        for (int e = 0; e < 4; ++e) {
          hv[tn][e]     = (__bf16)fmaxf(h0[e], 0.f);
          hv[tn][e + 4] = (__bf16)fmaxf(h1v[e], 0.f);
        }
      }
#pragma unroll
      for (int mt = 0; mt < 4; ++mt)
#pragma unroll
        for (int tn = 0; tn < 2; ++tn)
          acc[mt][tn] = __builtin_amdgcn_mfma_f32_16x16x32_bf16(
              wv[mt], hv[tn], acc[mt][tn], 0, 0, 0);
    }

    float s0 = 0.f, s1 = 0.f;
#pragma unroll
    for (int mt = 0; mt < 4; ++mt) {
      const f32x4 wv3 = *(const f32x4*)&w3s[(wm << 6) + (mt << 4) + (g << 2)];
#pragma unroll
      for (int p = 0; p < 4; ++p) {
        s0 = fmaf(fmaxf(acc[mt][0][p], 0.f), wv3[p], s0);
        s1 = fmaf(fmaxf(acc[mt][1][p], 0.f), wv3[p], s1);
      }
    }
    s0 += __shfl_xor(s0, 16);
    s0 += __shfl_xor(s0, 32);
    s1 += __shfl_xor(s1, 16);
    s1 += __shfl_xor(s1, 32);

    const int pb = t & 1;
    if (g == 0) {                                // 16 lanes, conflict-free
      part[pb][wm][(wn << 5) + c]      = s0;
      part[pb][wm][(wn << 5) + 16 + c] = s1;
    }

    __syncthreads();                             // one barrier per tile

    if (tid < 128) {
      const float v = part[pb][0][tid] + part[pb][1][tid] + bias3;
      out[(b << 12) + ((ip0 + t) << 7) + tid] = 1.f / (1.f + __expf(-v));
    }
  }
}

extern "C" void kernel_launch(void* const* d_in, const int* in_sizes, int n_in,
                              void* d_out, int out_size, void* d_ws,
                              size_t ws_size, hipStream_t stream)
{
  const float* af = (const float*)d_in[0];   // (128,64,128)
  const float* W1 = (const float*)d_in[1];   // (128,128)
  const float* b1 = (const float*)d_in[2];   // (128,)
  const float* W2 = (const float*)d_in[3];   // (128,128)
  const float* b2 = (const float*)d_in[4];   // (128,)
  const float* w3 = (const float*)d_in[5];   // (128,)
  const float* b3 = (const float*)d_in[6];   // (1,)
  const float* mw = (const float*)d_in[7];   // (64,)
  float* out = (float*)d_out;                // 524288 corr + 64 weights

  (void)d_ws; (void)ws_size;
  // one kernel: 512 blocks (2/CU), block = (b, i-quarter), 8 tiles each
  fused_kernel<<<512, 512, 0, stream>>>(af, W1, b1, W2, b2, w3, b3, mw, out);
}

// Round 8
// 95.508 us; speedup vs baseline: 1.7648x; 1.0878x over previous
//
#include <hip/hip_runtime.h>
#include <hip/hip_bf16.h>

// CorrelationNetwork — single fused kernel for MI355X (gfx950), round 12.
// R11 post-mortem: no spill, 2 blocks/CU achieved, but kernel 46.7->53us:
// the SCALAR prepass dominates (~10k cyc/SIMD fmaf issue + ~12us of LDS
// broadcast b128 reads per CU) and the 2nd block duplicates it (1.67x).
// Scalar prepass has no operand reuse; it's matmul-shaped -> use MFMA.
// R12: prepass = bf16x3-split MFMA GEMM (f=fh+fl, w=wh+wl; fh*wh+fh*wl+
// fl*wh, error ~2^-16 << the 2^-8 h1-bf16 quantization dominating absmax).
// 30 MFMA/wave replaces 1280 fmaf/thread. fl staged as hi/lo bf16 pad-72
// (2-way-conflict b128); W1T A-frags gathered from L2-resident global;
// b1 folded into Ai C-init. AjF/AiF layout + W2 gather + ajr + tile loop
// + epilogue verbatim R11.

typedef __bf16 bf16x8 __attribute__((ext_vector_type(8)));
typedef float f32x4 __attribute__((ext_vector_type(4)));

__device__ __forceinline__ unsigned rne16(float x) {
  unsigned u = __float_as_uint(x);
  u += 0x7fffu + ((u >> 16) & 1u);
  return u >> 16;
}
__device__ __forceinline__ __bf16 us_as_bf16(unsigned short s) {
  union { unsigned short s; __bf16 h; } cv; cv.s = s; return cv.h;
}

__global__ __launch_bounds__(512, 4) void fused_kernel(
    const float* __restrict__ af, const float* __restrict__ W1,
    const float* __restrict__ b1, const float* __restrict__ W2,
    const float* __restrict__ b2, const float* __restrict__ w3,
    const float* __restrict__ b3, const float* __restrict__ mw,
    float* __restrict__ out)
{
  // W2s (32 KB, tile phase) overlays flh/fll (18 KB, prepass staging)
  __shared__ __align__(16) unsigned short W2s[128 * 128];  // 32 KB
  __bf16* const flh = (__bf16*)W2s;                        // [64][72] hi
  __bf16* const fll = flh + 64 * 72;                       // [64][72] lo
  __shared__ __align__(16) float AjF[64 * 132];            // 33 KB, pad-132
  __shared__ __align__(16) float AiF[16 * 132];            // 8.25 KB
  __shared__ float b2s[128], w3s[128];
  __shared__ float part[2][2][128];                        // [tile&1][wm][row]

  const int tid  = threadIdx.x;
  const int lane = tid & 63;
  const int wave = tid >> 6;            // 0..7
  const int c = lane & 15, g = lane >> 4;
  const int wm = wave & 1;              // w2col half (64 cols)
  const int wn = wave >> 1;             // row quarter (32 rows)

  const int blk = blockIdx.x;
  const int b   = blk >> 2;             // 0..127
  const int iq  = blk & 3;              // i-quarter (8 i-pairs)
  const int ip0 = iq << 3;

  // ---- softmax of mixing weights (block 0, wave 0 only)
  if (blk == 0 && tid < 64) {
    float v = mw[tid];
    float m = v;
    for (int off = 32; off > 0; off >>= 1) m = fmaxf(m, __shfl_xor(m, off));
    float e = expf(v - m);
    float s = e;
    for (int off = 32; off > 0; off >>= 1) s += __shfl_xor(s, off);
    out[128 * 64 * 64 + tid] = e / s;
  }

  // ---- stage fl = af[b][0..63][0..63] split into bf16 hi/lo (pad-72 rows)
  {
    const float4* srcQ = (const float4*)(af + (b << 13));
#pragma unroll
    for (int p = 0; p < 2; ++p) {
      const int idx = (p << 9) + tid;            // 0..1023 float4s
      const int n = idx >> 4, e = idx & 15;
      const float4 v = srcQ[(n << 5) + e];
      const unsigned h0 = rne16(v.x), h1 = rne16(v.y),
                     h2 = rne16(v.z), h3 = rne16(v.w);
      const unsigned l0 = rne16(v.x - __uint_as_float(h0 << 16));
      const unsigned l1 = rne16(v.y - __uint_as_float(h1 << 16));
      const unsigned l2 = rne16(v.z - __uint_as_float(h2 << 16));
      const unsigned l3 = rne16(v.w - __uint_as_float(h3 << 16));
      uint2 ph; ph.x = h0 | (h1 << 16); ph.y = h2 | (h3 << 16);
      uint2 pl; pl.x = l0 | (l1 << 16); pl.y = l2 | (l3 << 16);
      *(uint2*)&flh[n * 72 + (e << 2)] = ph;
      *(uint2*)&fll[n * 72 + (e << 2)] = pl;
    }
    if (tid < 128) b2s[tid] = b2[tid];
    else if (tid < 256) w3s[tid - 128] = w3[tid - 128];
  }

  const float bias3 = b3[0];

  __syncthreads();                               // flh/fll, b2s/w3s ready

  // ---- MFMA prepass: wave w = htile (16 h-cols). D[m=h_loc][n=row] with
  // A = W1T frags (lane(c,g): h=w*16+c, f=base+g*8+e, hi/lo from global),
  // B = fl frags (lane(c,g): row=rt*16+c, f=base+g*8+e, hi/lo from LDS).
  // bf16x3: ah*bh + ah*bl + al*bh. Aj: rt 0..3 -> AjF; Ai: fl rows iq*16+c
  // -> AiF row c, C-init = b1.
  {
    const int w = wave;
    bf16x8 ajh[2], ajl[2], aih[2], ail[2];
#pragma unroll
    for (int kc = 0; kc < 2; ++kc) {
      const float* wpj = W1 + ((64 + (kc << 5) + (g << 3)) << 7) + (w << 4) + c;
      const float* wpi = W1 + (((kc << 5) + (g << 3)) << 7) + (w << 4) + c;
#pragma unroll
      for (int e = 0; e < 8; ++e) {
        const float vj = wpj[e << 7];
        const unsigned hj = rne16(vj);
        ajh[kc][e] = us_as_bf16((unsigned short)hj);
        ajl[kc][e] = us_as_bf16((unsigned short)rne16(vj - __uint_as_float(hj << 16)));
        const float vi = wpi[e << 7];
        const unsigned hi_ = rne16(vi);
        aih[kc][e] = us_as_bf16((unsigned short)hi_);
        ail[kc][e] = us_as_bf16((unsigned short)rne16(vi - __uint_as_float(hi_ << 16)));
      }
    }
#pragma unroll
    for (int rt = 0; rt < 4; ++rt) {
      const __bf16* bp = &flh[((rt << 4) + c) * 72 + (g << 3)];
      const __bf16* bq = &fll[((rt << 4) + c) * 72 + (g << 3)];
      f32x4 acc = {0.f, 0.f, 0.f, 0.f};
#pragma unroll
      for (int kc = 0; kc < 2; ++kc) {
        const bf16x8 bh = *(const bf16x8*)(bp + (kc << 5));
        const bf16x8 bl = *(const bf16x8*)(bq + (kc << 5));
        acc = __builtin_amdgcn_mfma_f32_16x16x32_bf16(ajh[kc], bh, acc, 0, 0, 0);
        acc = __builtin_amdgcn_mfma_f32_16x16x32_bf16(ajh[kc], bl, acc, 0, 0, 0);
        acc = __builtin_amdgcn_mfma_f32_16x16x32_bf16(ajl[kc], bh, acc, 0, 0, 0);
      }
      *(f32x4*)&AjF[((rt << 4) + c) * 132 + (w << 4) + (g << 2)] = acc;
    }
    {
      const __bf16* bp = &flh[((iq << 4) + c) * 72 + (g << 3)];
      const __bf16* bq = &fll[((iq << 4) + c) * 72 + (g << 3)];
      f32x4 acc = *(const f32x4*)(b1 + (w << 4) + (g << 2));
#pragma unroll
      for (int kc = 0; kc < 2; ++kc) {
        const bf16x8 bh = *(const bf16x8*)(bp + (kc << 5));
        const bf16x8 bl = *(const bf16x8*)(bq + (kc << 5));
        acc = __builtin_amdgcn_mfma_f32_16x16x32_bf16(aih[kc], bh, acc, 0, 0, 0);
        acc = __builtin_amdgcn_mfma_f32_16x16x32_bf16(aih[kc], bl, acc, 0, 0, 0);
        acc = __builtin_amdgcn_mfma_f32_16x16x32_bf16(ail[kc], bh, acc, 0, 0, 0);
      }
      *(f32x4*)&AiF[c * 132 + (w << 4) + (g << 2)] = acc;
    }
  }

  __syncthreads();                    // AjF/AiF ready; flh/fll dead

  // ---- W2 gather: f32 global -> RNE bf16 -> swizzled W2s (overlays flh).
  // Wave (wm, kt=wn); lane (c,g): m = wm*64+mt*16+c, k = kt*32+g*8+e,
  // chunk' = (kt*4+g)^c (R6-proven).
  {
    const int ktw = wn;
#pragma unroll
    for (int mt = 0; mt < 4; ++mt) {
      const int m = (wm << 6) + (mt << 4) + c;
      const float* wp = W2 + (((ktw << 5) + (g << 3)) << 7) + m;
      bf16x8 v;
#pragma unroll
      for (int e = 0; e < 8; ++e) {
        const float vv = wp[e << 7];
        v[e] = us_as_bf16((unsigned short)rne16(vv));
      }
      *(bf16x8*)&W2s[(m << 7) + ((((ktw << 2) + g) ^ c) << 3)] = v;
    }
  }

  // ---- tile-invariant Aj fragments -> registers (reads AjF, overlaps gather)
  f32x4 ajr[4][2][2];
#pragma unroll
  for (int kt = 0; kt < 4; ++kt)
#pragma unroll
    for (int tn = 0; tn < 2; ++tn) {
      const int j = ((wn << 5) + (tn << 4) + c) & 63;
      const float* ajb = &AjF[j * 132 + (g << 3) + (kt << 5)];
      ajr[kt][tn][0] = *(const f32x4*)(ajb);
      ajr[kt][tn][1] = *(const f32x4*)(ajb + 4);
    }

  __syncthreads();                               // W2s ready

  const int i_sel = wn >> 1;                     // row>=64 -> second i of pair

  for (int t = 0; t < 8; ++t) {
    const float* aib = &AiF[((t << 1) + i_sel) * 132 + (g << 3)];

    f32x4 acc[4][2];
#pragma unroll
    for (int mt = 0; mt < 4; ++mt) {
      const f32x4 bv = *(const f32x4*)&b2s[(wm << 6) + (mt << 4) + (g << 2)];
      acc[mt][0] = bv;
      acc[mt][1] = bv;
    }

#pragma unroll
    for (int kt = 0; kt < 4; ++kt) {
      const int es = ((kt << 2) + g) ^ c;
      bf16x8 wv[4];
#pragma unroll
      for (int mt = 0; mt < 4; ++mt)
        wv[mt] = *(const bf16x8*)&W2s[(((wm << 6) + (mt << 4) + c) << 7) + (es << 3)];

      const f32x4 a0 = *(const f32x4*)(aib + (kt << 5));
      const f32x4 a1 = *(const f32x4*)(aib + (kt << 5) + 4);
      bf16x8 hv[2];
#pragma unroll
      for (int tn = 0; tn < 2; ++tn) {
        const f32x4 h0  = a0 + ajr[kt][tn][0];
        const f32x4 h1v = a1 + ajr[kt][tn][1];
#pragma unroll
        for (int e = 0; e < 4; ++e) {
          hv[tn][e]     = (__bf16)fmaxf(h0[e], 0.f);
          hv[tn][e + 4] = (__bf16)fmaxf(h1v[e], 0.f);
        }
      }
#pragma unroll
      for (int mt = 0; mt < 4; ++mt)
#pragma unroll
        for (int tn = 0; tn < 2; ++tn)
          acc[mt][tn] = __builtin_amdgcn_mfma_f32_16x16x32_bf16(
              wv[mt], hv[tn], acc[mt][tn], 0, 0, 0);
    }

    float s0 = 0.f, s1 = 0.f;
#pragma unroll
    for (int mt = 0; mt < 4; ++mt) {
      const f32x4 wv3 = *(const f32x4*)&w3s[(wm << 6) + (mt << 4) + (g << 2)];
#pragma unroll
      for (int p = 0; p < 4; ++p) {
        s0 = fmaf(fmaxf(acc[mt][0][p], 0.f), wv3[p], s0);
        s1 = fmaf(fmaxf(acc[mt][1][p], 0.f), wv3[p], s1);
      }
    }
    s0 += __shfl_xor(s0, 16);
    s0 += __shfl_xor(s0, 32);
    s1 += __shfl_xor(s1, 16);
    s1 += __shfl_xor(s1, 32);

    const int pb = t & 1;
    if (g == 0) {                                // 16 lanes, conflict-free
      part[pb][wm][(wn << 5) + c]      = s0;
      part[pb][wm][(wn << 5) + 16 + c] = s1;
    }

    __syncthreads();                             // one barrier per tile

    if (tid < 128) {
      const float v = part[pb][0][tid] + part[pb][1][tid] + bias3;
      out[(b << 12) + ((ip0 + t) << 7) + tid] = 1.f / (1.f + __expf(-v));
    }
  }
}

extern "C" void kernel_launch(void* const* d_in, const int* in_sizes, int n_in,
                              void* d_out, int out_size, void* d_ws,
                              size_t ws_size, hipStream_t stream)
{
  const float* af = (const float*)d_in[0];   // (128,64,128)
  const float* W1 = (const float*)d_in[1];   // (128,128)
  const float* b1 = (const float*)d_in[2];   // (128,)
  const float* W2 = (const float*)d_in[3];   // (128,128)
  const float* b2 = (const float*)d_in[4];   // (128,)
  const float* w3 = (const float*)d_in[5];   // (128,)
  const float* b3 = (const float*)d_in[6];   // (1,)
  const float* mw = (const float*)d_in[7];   // (64,)
  float* out = (float*)d_out;                // 524288 corr + 64 weights

  (void)d_ws; (void)ws_size;
  // one kernel: 512 blocks (2/CU), block = (b, i-quarter), 8 tiles each
  fused_kernel<<<512, 512, 0, stream>>>(af, W1, b1, W2, b2, w3, b3, mw, out);
}